// Round 1
// baseline (2035.844 us; speedup 1.0000x reference)
//
#include <hip/hip_runtime.h>

#define NEGF (-1e30f)

constexpr int Bsz = 8;
constexpr int S   = 512;
constexpr int L   = 32;
constexpr int M   = 64;

// One block per batch. 256 threads: cur = t>>3 (0..31), jg = t&7 (8 lanes per label).
// Recurrence (factored):
//   alpha[fe][c] = LSE over j=1..min(M, fe+1) of
//       j <= fe      :  beta[fe-j][c] + seg[fe-j+1, fe, c]*j + diag[c]*(j-1)
//       j == fe+1<=M :  seg[0, fe, c]*j + diag[c]*(j-1)          (initial segment)
//   beta[p][c] = LSE over prev of ( alpha[p][prev] + T[prev][c] )
//   log_z = LSE_c alpha[S-1][c]
__launch_bounds__(256, 1)
__global__ void semicrf_fwd(const float* __restrict__ seg,
                            const float* __restrict__ trans,
                            float* __restrict__ out)
{
    const int t   = threadIdx.x;   // 0..255
    const int b   = blockIdx.x;    // 0..7
    const int cur = t >> 3;        // 0..31
    const int jg  = t & 7;         // 0..7

    __shared__ float T_s[32 * 33];     // T[prev][cur] at prev*33+cur (pad kills bank conflicts)
    __shared__ float ring[64 * 33];    // beta ring: frame p at (p&63)*33 + cur
    __shared__ float alpha_cur[32];

    // stage transitions into LDS (padded stride 33)
    for (int k = t; k < 1024; k += 256)
        T_s[(k >> 5) * 33 + (k & 31)] = trans[k];
    for (int k = t; k < 64 * 33; k += 256)
        ring[k] = NEGF;
    const float diag_c = trans[cur * 33];   // trans[cur*32 + cur]

    // alpha[0][c] = seg[b, 0, 0, c]
    if (t < 32)
        alpha_cur[t] = seg[(size_t)b * S * S * L + t];
    __syncthreads();

    // beta[0]
    {
        float m = NEGF, ss = 0.f;
        #pragma unroll
        for (int i = 0; i < 4; ++i) {
            const int prev = jg * 4 + i;
            const float v  = alpha_cur[prev] + T_s[prev * 33 + cur];
            const float mn = fmaxf(m, v);
            ss = ss * __expf(m - mn) + __expf(v - mn);
            m  = mn;
        }
        #pragma unroll
        for (int mask = 1; mask <= 4; mask <<= 1) {
            const float m2 = __shfl_xor(m, mask);
            const float s2 = __shfl_xor(ss, mask);
            const float mn = fmaxf(m, m2);
            ss = ss * __expf(m - mn) + s2 * __expf(m2 - mn);
            m  = mn;
        }
        if (jg == 0) ring[cur] = m + __logf(ss);
    }
    __syncthreads();

    // pointer to seg[b, 0, 0, cur]; element (start, fe): offset (start*S + fe)*L
    const float* segB = seg + (size_t)b * S * S * L + cur;

    // register double-buffer for the 8 segment scores this thread needs per step
    float sv[2][8];
    {
        #pragma unroll
        for (int i = 0; i < 8; ++i) {
            const int j0 = jg * 8 + i + 1;
            int st = 1 - j0 + 1;          // fe=1
            st = st < 0 ? 0 : st;
            sv[0][i] = segB[((size_t)st * S + 1) * L];
        }
    }

    for (int fe = 1; fe < S; ++fe) {
        const int cb = (fe - 1) & 1;

        // ---- prefetch fe+1 (flies across this whole step) ----
        {
            int fe2 = fe + 1; if (fe2 > S - 1) fe2 = S - 1;
            #pragma unroll
            for (int i = 0; i < 8; ++i) {
                const int j0 = jg * 8 + i + 1;
                int st = fe2 - j0 + 1;
                st = st < 0 ? 0 : st;
                sv[cb ^ 1][i] = segB[((size_t)st * S + fe2) * L];
            }
        }

        // ---- phase 1: alpha[fe][cur] ----
        float term[8];
        #pragma unroll
        for (int i = 0; i < 8; ++i) {
            const int j0 = jg * 8 + i + 1;   // segment length 1..64
            float tv = NEGF;
            if (j0 <= fe) {
                tv = ring[((fe - j0) & 63) * 33 + cur]
                   + sv[cb][i] * (float)j0 + diag_c * (float)(j0 - 1);
            } else if (j0 == fe + 1) {       // initial segment [0, fe]
                tv = sv[cb][i] * (float)j0 + diag_c * (float)(j0 - 1);
            }
            term[i] = tv;
        }
        float m = term[0];
        #pragma unroll
        for (int i = 1; i < 8; ++i) m = fmaxf(m, term[i]);
        float ss = 0.f;
        #pragma unroll
        for (int i = 0; i < 8; ++i) ss += __expf(term[i] - m);
        #pragma unroll
        for (int mask = 1; mask <= 4; mask <<= 1) {
            const float m2 = __shfl_xor(m, mask);
            const float s2 = __shfl_xor(ss, mask);
            const float mn = fmaxf(m, m2);
            ss = ss * __expf(m - mn) + s2 * __expf(m2 - mn);
            m  = mn;
        }
        if (jg == 0) alpha_cur[cur] = m + __logf(ss);
        __syncthreads();

        // ---- phase 2: beta[fe][cur] ----
        {
            float m2_ = NEGF, ss2 = 0.f;
            #pragma unroll
            for (int i = 0; i < 4; ++i) {
                const int prev = jg * 4 + i;
                const float v  = alpha_cur[prev] + T_s[prev * 33 + cur];
                const float mn = fmaxf(m2_, v);
                ss2 = ss2 * __expf(m2_ - mn) + __expf(v - mn);
                m2_ = mn;
            }
            #pragma unroll
            for (int mask = 1; mask <= 4; mask <<= 1) {
                const float mm = __shfl_xor(m2_, mask);
                const float s2 = __shfl_xor(ss2, mask);
                const float mn = fmaxf(m2_, mm);
                ss2 = ss2 * __expf(m2_ - mn) + s2 * __expf(mm - mn);
                m2_ = mn;
            }
            if (jg == 0) ring[(fe & 63) * 33 + cur] = m2_ + __logf(ss2);
        }
        __syncthreads();
    }

    // ---- final: log_z[b] = LSE_c alpha[S-1][c] (wave 0) ----
    if (t < 64) {
        float v  = (t < 32) ? alpha_cur[t] : NEGF;
        float m  = v;
        float ss = 1.f;
        #pragma unroll
        for (int mask = 1; mask <= 32; mask <<= 1) {
            const float m2 = __shfl_xor(m, mask);
            const float s2 = __shfl_xor(ss, mask);
            const float mn = fmaxf(m, m2);
            ss = ss * __expf(m - mn) + s2 * __expf(m2 - mn);
            m  = mn;
        }
        if (t == 0) out[b] = m + __logf(ss);
    }
}

extern "C" void kernel_launch(void* const* d_in, const int* in_sizes, int n_in,
                              void* d_out, int out_size, void* d_ws, size_t ws_size,
                              hipStream_t stream) {
    const float* seg   = (const float*)d_in[0];   // [8, 512, 512, 32] fp32
    const float* trans = (const float*)d_in[1];   // [32, 32] fp32
    float* out = (float*)d_out;                   // [8] fp32
    hipLaunchKernelGGL(semicrf_fwd, dim3(Bsz), dim3(256), 0, stream,
                       seg, trans, out);
}

// Round 3
// 869.771 us; speedup vs baseline: 2.3407x; 2.3407x over previous
//
#include <hip/hip_runtime.h>

#define NEGF (-1e30f)

constexpr int S = 512;
constexpr int L = 32;

// One block per batch. 256 threads: cur = t>>3 (0..31), jg = t&7.
// Factored recurrence:
//   alpha[fe][c] = LSE_{j=1..min(64,fe+1)} [ beta[fe-j][c] + seg[fe-j+1,fe,c]*j + diag[c]*(j-1) ]
//                  (j==fe+1 term has no beta — initial segment)
//   beta[p][c]   = LSE_prev ( alpha[p][prev] + T[prev][c] )
// Dataflow: ring (beta) columns are wave-local (wave = 8 curs; writer lane jg==0
// of column cur is in the same wave as all readers of column cur; same-wave DS
// ops execute in order) -> no barrier needed for ring. Only alpha crosses waves;
// alpha is double-buffered by fe-parity so ONE __syncthreads per step suffices.
// Segment scores are register-double-buffered with COMPILE-TIME buffer selection
// (2x unrolled loop) so they stay in VGPRs (runtime-indexed sv[cb][] spilled to
// scratch in R1: VGPR=40, ~8300 cyc/step).
// NOTE: macro-internal vars renamed (fe_v) — R2's `const int fe = (fe);`
// self-initialization UB was the failure cause.

#define PREFETCH(dst, fe_) do {                                              \
    int fe2 = (fe_); if (fe2 > S - 1) fe2 = S - 1;                           \
    _Pragma("unroll")                                                        \
    for (int i = 0; i < 8; ++i) {                                            \
        const int j0 = jg * 8 + i + 1;                                       \
        int st = fe2 - j0 + 1; st = st < 0 ? 0 : st;                         \
        dst[i] = segB[((size_t)st * S + fe2) * L];                           \
    }                                                                        \
} while (0)

#define STEP(fe_, sv, EARLY) do {                                            \
    const int fe_v = (fe_);                                                  \
    float term[8];                                                           \
    _Pragma("unroll")                                                        \
    for (int i = 0; i < 8; ++i) {                                            \
        const int j0 = jg * 8 + i + 1;                                       \
        const float base = fmaf(sv[i], (float)j0, diag_c * (float)(j0 - 1)); \
        float tv;                                                            \
        if (EARLY) {                                                         \
            tv = NEGF;                                                       \
            if (j0 <= fe_v)          tv = ring[((fe_v - j0) & 63) * 33 + cur] + base; \
            else if (j0 == fe_v + 1) tv = base;                              \
        } else {                                                             \
            tv = ring[((fe_v - j0) & 63) * 33 + cur] + base;                 \
        }                                                                    \
        term[i] = tv;                                                        \
    }                                                                        \
    float m = fmaxf(fmaxf(fmaxf(term[0], term[1]), fmaxf(term[2], term[3])), \
                    fmaxf(fmaxf(term[4], term[5]), fmaxf(term[6], term[7])));\
    float ss = ((__expf(term[0] - m) + __expf(term[1] - m)) +                \
                (__expf(term[2] - m) + __expf(term[3] - m))) +               \
               ((__expf(term[4] - m) + __expf(term[5] - m)) +                \
                (__expf(term[6] - m) + __expf(term[7] - m)));                \
    _Pragma("unroll")                                                        \
    for (int mk = 1; mk <= 4; mk <<= 1) {                                    \
        const float m2 = __shfl_xor(m, mk);                                  \
        const float s2 = __shfl_xor(ss, mk);                                 \
        const float mn = fmaxf(m, m2);                                       \
        ss = ss * __expf(m - mn) + s2 * __expf(m2 - mn);                     \
        m = mn;                                                              \
    }                                                                        \
    if (jg == 0) alpha[fe_v & 1][cur] = m + __logf(ss);                      \
    __syncthreads();                                                         \
    {                                                                        \
        const float* al = alpha[fe_v & 1];                                   \
        const float v0 = al[jg * 4 + 0] + T_s[(jg * 4 + 0) * 33 + cur];      \
        const float v1 = al[jg * 4 + 1] + T_s[(jg * 4 + 1) * 33 + cur];      \
        const float v2 = al[jg * 4 + 2] + T_s[(jg * 4 + 2) * 33 + cur];      \
        const float v3 = al[jg * 4 + 3] + T_s[(jg * 4 + 3) * 33 + cur];      \
        float bm = fmaxf(fmaxf(v0, v1), fmaxf(v2, v3));                      \
        float bs = (__expf(v0 - bm) + __expf(v1 - bm)) +                     \
                   (__expf(v2 - bm) + __expf(v3 - bm));                      \
        _Pragma("unroll")                                                    \
        for (int mk = 1; mk <= 4; mk <<= 1) {                                \
            const float m2 = __shfl_xor(bm, mk);                             \
            const float s2 = __shfl_xor(bs, mk);                             \
            const float mn = fmaxf(bm, m2);                                  \
            bs = bs * __expf(bm - mn) + s2 * __expf(m2 - mn);                \
            bm = mn;                                                         \
        }                                                                    \
        if (jg == 0) ring[(fe_v & 63) * 33 + cur] = bm + __logf(bs);         \
    }                                                                        \
} while (0)

__launch_bounds__(256, 1)
__global__ void semicrf_fwd(const float* __restrict__ seg,
                            const float* __restrict__ trans,
                            float* __restrict__ out)
{
    const int t   = threadIdx.x;
    const int b   = blockIdx.x;
    const int cur = t >> 3;
    const int jg  = t & 7;

    __shared__ float T_s[32 * 33];    // T[prev][cur] at prev*33+cur
    __shared__ float ring[64 * 33];   // beta ring, frame p at (p&63)*33+cur
    __shared__ float alpha[2][32];    // parity-double-buffered

    for (int k = t; k < 1024; k += 256)
        T_s[(k >> 5) * 33 + (k & 31)] = trans[k];
    for (int k = t; k < 64 * 33; k += 256)
        ring[k] = NEGF;
    const float diag_c = trans[cur * 33];

    if (t < 32)
        alpha[0][t] = seg[(size_t)b * S * S * L + t];   // alpha[0][c] = seg[b,0,0,c]
    __syncthreads();

    // beta[0] -> ring slot 0 (consumers are wave-local)
    {
        const float* al = alpha[0];
        const float v0 = al[jg * 4 + 0] + T_s[(jg * 4 + 0) * 33 + cur];
        const float v1 = al[jg * 4 + 1] + T_s[(jg * 4 + 1) * 33 + cur];
        const float v2 = al[jg * 4 + 2] + T_s[(jg * 4 + 2) * 33 + cur];
        const float v3 = al[jg * 4 + 3] + T_s[(jg * 4 + 3) * 33 + cur];
        float bm = fmaxf(fmaxf(v0, v1), fmaxf(v2, v3));
        float bs = (__expf(v0 - bm) + __expf(v1 - bm)) +
                   (__expf(v2 - bm) + __expf(v3 - bm));
        #pragma unroll
        for (int mk = 1; mk <= 4; mk <<= 1) {
            const float m2 = __shfl_xor(bm, mk);
            const float s2 = __shfl_xor(bs, mk);
            const float mn = fmaxf(bm, m2);
            bs = bs * __expf(bm - mn) + s2 * __expf(m2 - mn);
            bm = mn;
        }
        if (jg == 0) ring[cur] = bm + __logf(bs);
    }

    const float* segB = seg + (size_t)b * S * S * L + cur;

    float svA[8], svB[8];
    PREFETCH(svA, 1);

    // EARLY: fe = 1..64 (guarded: init segment + short-history)
    for (int fe = 1; fe <= 63; fe += 2) {
        PREFETCH(svB, fe + 1);
        STEP(fe, svA, true);
        PREFETCH(svA, fe + 2);
        STEP(fe + 1, svB, true);
    }
    // CLEAN: fe = 65..510 (branch-free window)
    for (int fe = 65; fe <= 509; fe += 2) {
        PREFETCH(svB, fe + 1);
        STEP(fe, svA, false);
        PREFETCH(svA, fe + 2);
        STEP(fe + 1, svB, false);
    }
    // tail: fe = 511 (svA was prefetched for 511 in the last clean iteration)
    STEP(511, svA, false);

    // log_z[b] = LSE_c alpha[S-1][c]; alpha[511&1]=alpha[1] complete after the
    // tail STEP's internal barrier.
    if (t < 64) {
        float v  = (t < 32) ? alpha[1][t] : NEGF;
        float m  = v;
        float ss = 1.f;
        #pragma unroll
        for (int mk = 1; mk <= 32; mk <<= 1) {
            const float m2 = __shfl_xor(m, mk);
            const float s2 = __shfl_xor(ss, mk);
            const float mn = fmaxf(m, m2);
            ss = ss * __expf(m - mn) + s2 * __expf(m2 - mn);
            m  = mn;
        }
        if (t == 0) out[b] = m + __logf(ss);
    }
}

extern "C" void kernel_launch(void* const* d_in, const int* in_sizes, int n_in,
                              void* d_out, int out_size, void* d_ws, size_t ws_size,
                              hipStream_t stream) {
    const float* seg   = (const float*)d_in[0];   // [8, 512, 512, 32] fp32
    const float* trans = (const float*)d_in[1];   // [32, 32] fp32
    float* out = (float*)d_out;                   // [8] fp32
    hipLaunchKernelGGL(semicrf_fwd, dim3(8), dim3(256), 0, stream,
                       seg, trans, out);
}

// Round 4
// 696.666 us; speedup vs baseline: 2.9223x; 1.2485x over previous
//
#include <hip/hip_runtime.h>

#define NEGF (-1e30f)

constexpr int S = 512;
constexpr int L = 32;

// One block per batch. 256 threads: cur = t>>3 (0..31), jg = t&7.
// Factored recurrence:
//   alpha[fe][c] = LSE_{j=1..min(64,fe+1)} [ beta[fe-j][c] + seg[fe-j+1,fe,c]*j + diag[c]*(j-1) ]
//                  (j == fe+1 term has no beta — initial segment)
//   beta[p][c]   = LSE_prev ( alpha[p][prev] + T[prev][c] )
//                = mx + log( sum_prev exp(alpha[p][prev]-mx) * E[prev][c] ),  E = exp(T)
// R4 changes vs R3 (597us):
//  - all 8-lane LSE merges via DPP (quad_perm xor1/xor2 + ROW_HALF_MIRROR=xor7;
//    {1,2,7} generates the 8-group) — VALU pipe, ~8cyc latency, replaces
//    ds_swizzle shuffles (~60-100cyc each, 6 rounds on the serial chain).
//  - two-pass LSE: DPP max-reduce first, then independent exps, then DPP
//    sum-reduce — no transcendentals inside the merge rounds.
//  - phase 2 in linear space with E=exp(T) held in 4 registers/lane; the 4
//    alphas arrive as one ds_read_b128 (same-address broadcast across curs).
//  - T_s and ring-init removed (EARLY guards never read unwritten ring rows).

template <int CTRL>
__device__ __forceinline__ float dppf(float x) {
    return __builtin_bit_cast(float,
        __builtin_amdgcn_update_dpp(0, __builtin_bit_cast(int, x),
                                    CTRL, 0xf, 0xf, true));
}
// 8-lane-group reduce, result valid in ALL 8 lanes.
#define GR8_MAX(v) do { v = fmaxf(v, dppf<0xB1>(v));   /* xor1  */ \
                        v = fmaxf(v, dppf<0x4E>(v));   /* xor2  */ \
                        v = fmaxf(v, dppf<0x141>(v)); } while (0)  /* xor7 */
#define GR8_ADD(v) do { v += dppf<0xB1>(v);                        \
                        v += dppf<0x4E>(v);                        \
                        v += dppf<0x141>(v); } while (0)

#define PREFETCH(dst, fe_) do {                                              \
    int fe2 = (fe_); if (fe2 > S - 1) fe2 = S - 1;                           \
    _Pragma("unroll")                                                        \
    for (int i = 0; i < 8; ++i) {                                            \
        const int j0 = jg * 8 + i + 1;                                       \
        int st = fe2 - j0 + 1; st = st < 0 ? 0 : st;                         \
        dst[i] = segB[((size_t)st * S + fe2) * L];                           \
    }                                                                        \
} while (0)

// phase 2 (+ ring write) for frame p_ using alpha[p_ & 1]
#define PHASE2(p_) do {                                                      \
    const int p_v = (p_);                                                    \
    const float4 a4 = *(const float4*)&alpha[p_v & 1][jg * 4];               \
    float mx = fmaxf(fmaxf(a4.x, a4.y), fmaxf(a4.z, a4.w));                  \
    GR8_MAX(mx);                                                             \
    float sb = __expf(a4.x - mx) * E0 + __expf(a4.y - mx) * E1               \
             + __expf(a4.z - mx) * E2 + __expf(a4.w - mx) * E3;              \
    GR8_ADD(sb);                                                             \
    if (jg == 0) ring[(p_v & 63) * 33 + cur] = mx + __logf(sb);              \
} while (0)

#define STEP(fe_, sv, EARLY) do {                                           \
    const int fe_v = (fe_);                                                 \
    float term[8];                                                          \
    _Pragma("unroll")                                                       \
    for (int i = 0; i < 8; ++i) {                                           \
        const int j0 = jg * 8 + i + 1;                                      \
        const float base = fmaf(sv[i], (float)j0, diag_c * (float)(j0 - 1));\
        float tv;                                                           \
        if (EARLY) {                                                        \
            tv = NEGF;                                                      \
            if (j0 <= fe_v)          tv = ring[((fe_v - j0) & 63) * 33 + cur] + base; \
            else if (j0 == fe_v + 1) tv = base;                             \
        } else {                                                            \
            tv = ring[((fe_v - j0) & 63) * 33 + cur] + base;                \
        }                                                                   \
        term[i] = tv;                                                       \
    }                                                                       \
    float M = fmaxf(fmaxf(fmaxf(term[0], term[1]), fmaxf(term[2], term[3])),\
                    fmaxf(fmaxf(term[4], term[5]), fmaxf(term[6], term[7])));\
    GR8_MAX(M);                                                             \
    float ss = ((__expf(term[0] - M) + __expf(term[1] - M)) +               \
                (__expf(term[2] - M) + __expf(term[3] - M))) +              \
               ((__expf(term[4] - M) + __expf(term[5] - M)) +               \
                (__expf(term[6] - M) + __expf(term[7] - M)));               \
    GR8_ADD(ss);                                                            \
    if (jg == 0) alpha[fe_v & 1][cur] = M + __logf(ss);                     \
    __syncthreads();                                                        \
    PHASE2(fe_v);                                                           \
} while (0)

__launch_bounds__(256, 1)
__global__ void semicrf_fwd(const float* __restrict__ seg,
                            const float* __restrict__ trans,
                            float* __restrict__ out)
{
    const int t   = threadIdx.x;
    const int b   = blockIdx.x;
    const int cur = t >> 3;
    const int jg  = t & 7;

    __shared__ float ring[64 * 33];   // beta ring, frame p at (p&63)*33+cur
    __shared__ float alpha[2][32];    // parity-double-buffered

    const float diag_c = trans[cur * 33];            // trans[cur][cur]
    // E[prev][cur] = exp(T[prev][cur]) for this lane's 4 prevs (jg*4..jg*4+3)
    const float E0 = __expf(trans[(jg * 4 + 0) * 32 + cur]);
    const float E1 = __expf(trans[(jg * 4 + 1) * 32 + cur]);
    const float E2 = __expf(trans[(jg * 4 + 2) * 32 + cur]);
    const float E3 = __expf(trans[(jg * 4 + 3) * 32 + cur]);

    if (t < 32)
        alpha[0][t] = seg[(size_t)b * S * S * L + t];   // alpha[0][c] = seg[b,0,0,c]
    __syncthreads();
    PHASE2(0);                                          // beta[0] -> ring row 0

    const float* segB = seg + (size_t)b * S * S * L + cur;

    float svA[8], svB[8];
    PREFETCH(svA, 1);

    // EARLY: fe = 1..64 (guarded: init segment + short history)
    for (int fe = 1; fe <= 63; fe += 2) {
        PREFETCH(svB, fe + 1);
        STEP(fe, svA, true);
        PREFETCH(svA, fe + 2);
        STEP(fe + 1, svB, true);
    }
    // CLEAN: fe = 65..510 (branch-free 64-wide window)
    for (int fe = 65; fe <= 509; fe += 2) {
        PREFETCH(svB, fe + 1);
        STEP(fe, svA, false);
        PREFETCH(svA, fe + 2);
        STEP(fe + 1, svB, false);
    }
    // tail: fe = 511 (svA was prefetched in the last clean iteration)
    STEP(511, svA, false);

    // log_z[b] = LSE_c alpha[S-1][c]; alpha[511&1]=alpha[1] complete after the
    // tail STEP's internal barrier.
    if (t < 64) {
        float v  = (t < 32) ? alpha[1][t] : NEGF;
        float m  = v;
        float ss = 1.f;
        #pragma unroll
        for (int mk = 1; mk <= 32; mk <<= 1) {
            const float m2 = __shfl_xor(m, mk);
            const float s2 = __shfl_xor(ss, mk);
            const float mn = fmaxf(m, m2);
            ss = ss * __expf(m - mn) + s2 * __expf(m2 - mn);
            m  = mn;
        }
        if (t == 0) out[b] = m + __logf(ss);
    }
}

extern "C" void kernel_launch(void* const* d_in, const int* in_sizes, int n_in,
                              void* d_out, int out_size, void* d_ws, size_t ws_size,
                              hipStream_t stream) {
    const float* seg   = (const float*)d_in[0];   // [8, 512, 512, 32] fp32
    const float* trans = (const float*)d_in[1];   // [32, 32] fp32
    float* out = (float*)d_out;                   // [8] fp32
    hipLaunchKernelGGL(semicrf_fwd, dim3(8), dim3(256), 0, stream,
                       seg, trans, out);
}

// Round 5
// 693.247 us; speedup vs baseline: 2.9367x; 1.0049x over previous
//
#include <hip/hip_runtime.h>

#define NEGF (-1e30f)

constexpr int S = 512;
constexpr int L = 32;

// One block per batch. 256 threads: cur = t>>3 (0..31), jg = t&7.
// Factored recurrence:
//   alpha[fe][c] = LSE_{j=1..min(64,fe+1)} [ beta[fe-j][c] + seg[fe-j+1,fe,c]*j + diag[c]*(j-1) ]
//                  (j == fe+1 term has no beta — initial segment)
//   beta[p][c]   = LSE_prev ( alpha[p][prev] + T[prev][c] )
//                = mx + log( sum_prev exp(alpha[p][prev]-mx) * E[prev][c] ),  E = exp(T)
// R5 changes vs R4 (420us):
//  - __syncthreads() lowered to `s_waitcnt vmcnt(0); s_barrier` and drained the
//    per-step prefetch (cold-HBM column fe+1, ~900cyc) INSIDE every step.
//    Replaced with an LDS-only barrier: fence(workgroup,"local") + s_barrier +
//    fence — legalizer emits only lgkmcnt(0); global loads stay in flight.
//  - prefetch distance 2 (4 register buffers, loop unrolled x4) so each seg
//    column has >1200cyc to fly before first use.

template <int CTRL>
__device__ __forceinline__ float dppf(float x) {
    return __builtin_bit_cast(float,
        __builtin_amdgcn_update_dpp(0, __builtin_bit_cast(int, x),
                                    CTRL, 0xf, 0xf, true));
}
// 8-lane-group reduce, result valid in ALL 8 lanes ({xor1,xor2,xor7} generates the group).
#define GR8_MAX(v) do { v = fmaxf(v, dppf<0xB1>(v));   /* quad_perm xor1 */ \
                        v = fmaxf(v, dppf<0x4E>(v));   /* quad_perm xor2 */ \
                        v = fmaxf(v, dppf<0x141>(v)); } while (0) /* row_half_mirror = xor7 */
#define GR8_ADD(v) do { v += dppf<0xB1>(v);                                 \
                        v += dppf<0x4E>(v);                                 \
                        v += dppf<0x141>(v); } while (0)

// LDS-only workgroup barrier: orders LDS, does NOT drain vmcnt.
#define LDS_BARRIER() do {                                                  \
    __builtin_amdgcn_fence(__ATOMIC_RELEASE, "workgroup", "local");         \
    __builtin_amdgcn_s_barrier();                                           \
    __builtin_amdgcn_fence(__ATOMIC_ACQUIRE, "workgroup", "local");         \
} while (0)

#define PREFETCH(dst, fe_) do {                                             \
    int fe2 = (fe_); if (fe2 > S - 1) fe2 = S - 1;                          \
    _Pragma("unroll")                                                       \
    for (int i = 0; i < 8; ++i) {                                           \
        const int j0 = jg * 8 + i + 1;                                      \
        int st = fe2 - j0 + 1; st = st < 0 ? 0 : st;                        \
        dst[i] = segB[((size_t)st * S + fe2) * L];                          \
    }                                                                       \
} while (0)

// phase 2 (+ ring write) for frame p_ using alpha[p_ & 1]
#define PHASE2(p_) do {                                                     \
    const int p_v = (p_);                                                   \
    const float4 a4 = *(const float4*)&alpha[p_v & 1][jg * 4];              \
    float mx = fmaxf(fmaxf(a4.x, a4.y), fmaxf(a4.z, a4.w));                 \
    GR8_MAX(mx);                                                            \
    float sb = __expf(a4.x - mx) * E0 + __expf(a4.y - mx) * E1              \
             + __expf(a4.z - mx) * E2 + __expf(a4.w - mx) * E3;             \
    GR8_ADD(sb);                                                            \
    if (jg == 0) ring[(p_v & 63) * 33 + cur] = mx + __logf(sb);             \
} while (0)

#define STEP(fe_, sv, EARLY) do {                                           \
    const int fe_v = (fe_);                                                 \
    float term[8];                                                          \
    _Pragma("unroll")                                                       \
    for (int i = 0; i < 8; ++i) {                                           \
        const int j0 = jg * 8 + i + 1;                                      \
        const float base = fmaf(sv[i], (float)j0, diag_c * (float)(j0 - 1));\
        float tv;                                                           \
        if (EARLY) {                                                        \
            tv = NEGF;                                                      \
            if (j0 <= fe_v)          tv = ring[((fe_v - j0) & 63) * 33 + cur] + base; \
            else if (j0 == fe_v + 1) tv = base;                             \
        } else {                                                            \
            tv = ring[((fe_v - j0) & 63) * 33 + cur] + base;                \
        }                                                                   \
        term[i] = tv;                                                       \
    }                                                                       \
    float M = fmaxf(fmaxf(fmaxf(term[0], term[1]), fmaxf(term[2], term[3])),\
                    fmaxf(fmaxf(term[4], term[5]), fmaxf(term[6], term[7])));\
    GR8_MAX(M);                                                             \
    float ss = ((__expf(term[0] - M) + __expf(term[1] - M)) +               \
                (__expf(term[2] - M) + __expf(term[3] - M))) +              \
               ((__expf(term[4] - M) + __expf(term[5] - M)) +               \
                (__expf(term[6] - M) + __expf(term[7] - M)));               \
    GR8_ADD(ss);                                                            \
    if (jg == 0) alpha[fe_v & 1][cur] = M + __logf(ss);                     \
    LDS_BARRIER();                                                          \
    PHASE2(fe_v);                                                           \
} while (0)

__launch_bounds__(256, 1)
__global__ void semicrf_fwd(const float* __restrict__ seg,
                            const float* __restrict__ trans,
                            float* __restrict__ out)
{
    const int t   = threadIdx.x;
    const int b   = blockIdx.x;
    const int cur = t >> 3;
    const int jg  = t & 7;

    __shared__ float ring[64 * 33];   // beta ring, frame p at (p&63)*33+cur
    __shared__ float alpha[2][32];    // parity-double-buffered

    const float diag_c = trans[cur * 33];            // trans[cur][cur]
    // E[prev][cur] = exp(T[prev][cur]) for this lane's 4 prevs (jg*4..jg*4+3)
    const float E0 = __expf(trans[(jg * 4 + 0) * 32 + cur]);
    const float E1 = __expf(trans[(jg * 4 + 1) * 32 + cur]);
    const float E2 = __expf(trans[(jg * 4 + 2) * 32 + cur]);
    const float E3 = __expf(trans[(jg * 4 + 3) * 32 + cur]);

    if (t < 32)
        alpha[0][t] = seg[(size_t)b * S * S * L + t];   // alpha[0][c] = seg[b,0,0,c]
    __syncthreads();                                    // before any prefetch: free
    PHASE2(0);                                          // beta[0] -> ring row 0

    const float* segB = seg + (size_t)b * S * S * L + cur;

    float sv0[8], sv1[8], sv2[8], sv3[8];
    PREFETCH(sv0, 1);
    PREFETCH(sv1, 2);

    // EARLY: fe = 1..64 (guarded: init segment + short history)
    for (int fe = 1; fe <= 61; fe += 4) {
        PREFETCH(sv2, fe + 2); STEP(fe + 0, sv0, true);
        PREFETCH(sv3, fe + 3); STEP(fe + 1, sv1, true);
        PREFETCH(sv0, fe + 4); STEP(fe + 2, sv2, true);
        PREFETCH(sv1, fe + 5); STEP(fe + 3, sv3, true);
    }
    // CLEAN: fe = 65..508 (branch-free 64-wide window)
    for (int fe = 65; fe <= 505; fe += 4) {
        PREFETCH(sv2, fe + 2); STEP(fe + 0, sv0, false);
        PREFETCH(sv3, fe + 3); STEP(fe + 1, sv1, false);
        PREFETCH(sv0, fe + 4); STEP(fe + 2, sv2, false);
        PREFETCH(sv1, fe + 5); STEP(fe + 3, sv3, false);
    }
    // tail: fe = 509..511 (sv0=509, sv1=510 already in flight)
    PREFETCH(sv2, 511);
    STEP(509, sv0, false);
    STEP(510, sv1, false);
    STEP(511, sv2, false);

    // log_z[b] = LSE_c alpha[S-1][c]; alpha[511&1]=alpha[1] complete after the
    // tail STEP's internal barrier.
    if (t < 64) {
        float v  = (t < 32) ? alpha[1][t] : NEGF;
        float m  = v;
        float ss = 1.f;
        #pragma unroll
        for (int mk = 1; mk <= 32; mk <<= 1) {
            const float m2 = __shfl_xor(m, mk);
            const float s2 = __shfl_xor(ss, mk);
            const float mn = fmaxf(m, m2);
            ss = ss * __expf(m - mn) + s2 * __expf(m2 - mn);
            m  = mn;
        }
        if (t == 0) out[b] = m + __logf(ss);
    }
}

extern "C" void kernel_launch(void* const* d_in, const int* in_sizes, int n_in,
                              void* d_out, int out_size, void* d_ws, size_t ws_size,
                              hipStream_t stream) {
    const float* seg   = (const float*)d_in[0];   // [8, 512, 512, 32] fp32
    const float* trans = (const float*)d_in[1];   // [32, 32] fp32
    float* out = (float*)d_out;                   // [8] fp32
    hipLaunchKernelGGL(semicrf_fwd, dim3(8), dim3(256), 0, stream,
                       seg, trans, out);
}